// Round 1
// 130.169 us; speedup vs baseline: 1.0134x; 1.0134x over previous
//
#include <hip/hip_runtime.h>
#include <hip/hip_fp16.h>
#include <math.h>

#define CC 64
#define KK 16
#define NNODES 15
#define DD 512      // input feature dim
#define MM 512      // output dim
#define NN 16384    // rows

typedef _Float16 half8 __attribute__((ext_vector_type(8)));
typedef float f32x4 __attribute__((ext_vector_type(4)));
typedef unsigned long long u64;

// ---------------------------------------------------------------------------
// XLA/Eigen fast-tanh for f32 (bit-exact vs JAX's jnp.tanh lowering).
// Round 3/4/5 evidence: required to match the golden's argmax codes.
// ---------------------------------------------------------------------------
__device__ __forceinline__ float xla_tanhf(float x) {
    const float kMax = 7.90531110763549805f;
    bool tiny = fabsf(x) < 0.0004f;
    float xc = fminf(fmaxf(x, -kMax), kMax);
    float x2 = __fmul_rn(xc, xc);
    float p = __fmaf_rn(x2, -2.76076847742355e-16f, 2.00018790482477e-13f);
    p = __fmaf_rn(x2, p, -8.60467152213735e-11f);
    p = __fmaf_rn(x2, p, 5.12229709037114e-08f);
    p = __fmaf_rn(x2, p, 1.48572235717979e-05f);
    p = __fmaf_rn(x2, p, 6.37261928875436e-04f);
    p = __fmaf_rn(x2, p, 4.89352455891786e-03f);
    p = __fmul_rn(xc, p);
    float q = __fmaf_rn(x2, 1.19825839466702e-06f, 1.18534705686654e-04f);
    q = __fmaf_rn(x2, q, 2.26843463243900e-03f);
    q = __fmaf_rn(x2, q, 4.89352518554385e-03f);
    return tiny ? x : __fdiv_rn(p, q);
}

// ---------------------------------------------------------------------------
// Kernel 1: pack L (M, C, K) fp32 -> Bpk fp16 in MFMA-B fragment order.
// B operand of mfma_f32_16x16x32_f16: lane l holds B[k=(l>>4)*8+j][col=l&15],
// j = 0..7 packed in 4 VGPRs. Layout: Bpk[ks][mtile][lane] = uint4 (8 halves).
// Thread t IS the destination uint4 index; each thread reads 32B contiguous
// from L (slot window is 8-aligned inside one subspace) and writes coalesced.
// ---------------------------------------------------------------------------
__global__ __launch_bounds__(256) void pack_bfrag(const float* __restrict__ L,
                                                  uint4* __restrict__ Bpk) {
    const int t    = blockIdx.x * 256 + threadIdx.x;  // 0..65535
    const int lane = t & 63;
    const int mtg  = (t >> 6) & 31;                   // global m-tile 0..31
    const int ks   = t >> 11;                         // k-step 0..31
    const int kbase = ks * 32 + ((lane >> 4) << 3);   // 8-aligned k window
    const int c     = kbase >> 4;                     // subspace
    const int slot0 = kbase & 15;                     // 0 or 8
    const int m     = (mtg << 4) + (lane & 15);

    const float* src = L + ((size_t)m * CC + c) * KK + slot0;
    float4 v0 = ((const float4*)src)[0];
    float4 v1 = ((const float4*)src)[1];
    union { half8 h; uint4 u; } pk;
    pk.h[0] = (_Float16)v0.x; pk.h[1] = (_Float16)v0.y;
    pk.h[2] = (_Float16)v0.z; pk.h[3] = (_Float16)v0.w;
    pk.h[4] = (_Float16)v1.x; pk.h[5] = (_Float16)v1.y;
    pk.h[6] = (_Float16)v1.z; pk.h[7] = (_Float16)v1.w;
    Bpk[t] = pk.u;
}

// ---------------------------------------------------------------------------
// Kernel 2: FUSED encode + MFMA decode.
// Block: 64 rows x 256 cols, 4 waves; wave w owns all 64 rows x 64 cols
// (4 n-tiles x 4 m-tiles -> 4x B-fragment register reuse: L2 B traffic
// 1.07GB -> 268MB). Encode: bit-exact round-5 math, 16 rows/thread, codes
// into LDS [c][row] (stride 68: conflict-free reads AND writes). Decode:
// 32 k-steps, one-hot fp16 A built from codes (two u64 shifts), B frags
// double-buffered from L2-resident Bpk, fp32 MFMA accumulate.
// ---------------------------------------------------------------------------
__global__ __launch_bounds__(256, 2) void fused_mfma(const float* __restrict__ I,
                                                     const float* __restrict__ A,
                                                     const float* __restrict__ T,
                                                     const uint4* __restrict__ Bpk,
                                                     float* __restrict__ out) {
    __shared__ float sA[32 * 64];              // TRANSPOSED: [s*4+d][c] — kills 32-way conflict
    __shared__ float sT[CC * NNODES];          // [c*15+i], stride 15 dwords: spread
    __shared__ unsigned char sCodes[CC * 68];  // [c][row_local], stride 68 (17 dwords, odd)

    const int tid = threadIdx.x;
    for (int i = tid; i < CC * 32; i += 256) sA[(i & 31) * 64 + (i >> 5)] = A[i];
    for (int i = tid; i < CC * NNODES; i += 256) sT[i] = T[i];
    __syncthreads();

    const int w    = tid >> 6;
    const int lane = tid & 63;
    const int n0 = (blockIdx.x >> 1) * 64;
    const int m0 = (blockIdx.x & 1) * 256 + w * 64;

    // ---------------- encode (bit-exact round-5 math; 16 rows/thread) ----------------
    {
        const int c = lane;
        const int lvl[NNODES] = {0, 1, 1, 2, 2, 2, 2, 3, 3, 3, 3, 3, 3, 3, 3};
#pragma unroll 2
        for (int rr = 0; rr < 16; ++rr) {
            const int rl = (rr << 2) + w;     // row_local 0..63
            const float* Ij = I + (size_t)(n0 + rl) * DD + c * 8;  // wave reads 2KB contiguous
            float4 v0 = ((const float4*)Ij)[0];
            float4 v1 = ((const float4*)Ij)[1];
            float iv[8] = {v0.x, v0.y, v0.z, v0.w, v1.x, v1.y, v1.z, v1.w};

            float t[4] = {0.f, 0.f, 0.f, 0.f};
#pragma unroll
            for (int s = 0; s < 8; ++s) {
                float v = iv[s];
#pragma unroll
                for (int d = 0; d < 4; ++d)
                    t[d] = __fmaf_rn(v, sA[((s << 2) + d) * 64 + c], t[d]);
            }

            float th[NNODES];
#pragma unroll
            for (int i = 0; i < NNODES; ++i) {
                float h = __fsub_rn(t[lvl[i]], sT[c * NNODES + i]);
                th[i] = xla_tanhf(h);
            }

            int best = 0;
            float bestv = -3.0e38f;
#pragma unroll
            for (int k = 0; k < KK; ++k) {
                int node = 0;
                float s = 0.f;
#pragma unroll
                for (int l = 0; l < 4; ++l) {
                    int bit = (k >> (3 - l)) & 1;
                    s = __fadd_rn(s, bit ? th[node] : -th[node]);
                    node = 2 * node + 1 + bit;
                }
                if (s > bestv) { bestv = s; best = k; }   // strict >: first-max
            }
            sCodes[c * 68 + rl] = (unsigned char)best;
        }
    }
    __syncthreads();

    // ---------------- decode: one-hot fp16 MFMA GEMM ----------------
    const int r15  = lane & 15;                 // A row index within n-tile
    const int sb   = ((lane >> 4) & 1) << 3;    // slot base (0 or 8) of this lane's k-window
    const int chi  = lane >> 5;                 // which of the 2 subspaces per k-step
    const int mtg0 = m0 >> 4;                   // this wave's first global m-tile

    f32x4 acc[4][4];
#pragma unroll
    for (int nt = 0; nt < 4; ++nt)
#pragma unroll
        for (int mt = 0; mt < 4; ++mt)
            acc[nt][mt] = (f32x4){0.f, 0.f, 0.f, 0.f};

    const uint4* Bp = Bpk + (size_t)mtg0 * 64 + lane;   // + (ks*32+mt)*64 per frag

    uint4 bA[4], bB[4];
#pragma unroll
    for (int mt = 0; mt < 4; ++mt) bA[mt] = Bp[mt * 64];

    for (int ks = 0; ks < 32; ks += 2) {
        // prefetch ks+1 (always valid: ks <= 30)
#pragma unroll
        for (int mt = 0; mt < 4; ++mt) bB[mt] = Bp[((ks + 1) * 32 + mt) * 64];

        // A one-hot frags for ks
        half8 a0[4];
        {
            const int c0 = (ks << 1) + chi;
#pragma unroll
            for (int nt = 0; nt < 4; ++nt) {
                unsigned ud = (unsigned)((int)sCodes[c0 * 68 + (nt << 4) + r15] - sb);
                unsigned ud2 = ud - 4u;
                u64 lo = (ud  < 4u) ? (0x3C00ull << ((ud  & 3u) << 4)) : 0ull;
                u64 hi = (ud2 < 4u) ? (0x3C00ull << ((ud2 & 3u) << 4)) : 0ull;
                union { u64 q[2]; half8 h; } uu; uu.q[0] = lo; uu.q[1] = hi;
                a0[nt] = uu.h;
            }
        }
#pragma unroll
        for (int nt = 0; nt < 4; ++nt)
#pragma unroll
            for (int mt = 0; mt < 4; ++mt) {
                union { uint4 u; half8 h; } bb; bb.u = bA[mt];
                acc[nt][mt] = __builtin_amdgcn_mfma_f32_16x16x32_f16(a0[nt], bb.h, acc[nt][mt], 0, 0, 0);
            }

        if (ks + 2 < 32) {
#pragma unroll
            for (int mt = 0; mt < 4; ++mt) bA[mt] = Bp[((ks + 2) * 32 + mt) * 64];
        }

        // A one-hot frags for ks+1
        half8 a1[4];
        {
            const int c1 = ((ks + 1) << 1) + chi;
#pragma unroll
            for (int nt = 0; nt < 4; ++nt) {
                unsigned ud = (unsigned)((int)sCodes[c1 * 68 + (nt << 4) + r15] - sb);
                unsigned ud2 = ud - 4u;
                u64 lo = (ud  < 4u) ? (0x3C00ull << ((ud  & 3u) << 4)) : 0ull;
                u64 hi = (ud2 < 4u) ? (0x3C00ull << ((ud2 & 3u) << 4)) : 0ull;
                union { u64 q[2]; half8 h; } uu; uu.q[0] = lo; uu.q[1] = hi;
                a1[nt] = uu.h;
            }
        }
#pragma unroll
        for (int nt = 0; nt < 4; ++nt)
#pragma unroll
            for (int mt = 0; mt < 4; ++mt) {
                union { uint4 u; half8 h; } bb; bb.u = bB[mt];
                acc[nt][mt] = __builtin_amdgcn_mfma_f32_16x16x32_f16(a1[nt], bb.h, acc[nt][mt], 0, 0, 0);
            }
    }

    // ---------------- epilogue: D layout col=lane&15, row=(lane>>4)*4+reg ----------------
    const int rbase = (lane >> 4) << 2;
#pragma unroll
    for (int nt = 0; nt < 4; ++nt) {
#pragma unroll
        for (int r = 0; r < 4; ++r) {
            float* o = out + (size_t)(n0 + (nt << 4) + rbase + r) * MM + m0 + r15;
#pragma unroll
            for (int mt = 0; mt < 4; ++mt)
                o[mt << 4] = acc[nt][mt][r];   // 16 lanes x 4B consecutive: 64B segments
        }
    }
}

// ---------------------------------------------------------------------------
extern "C" void kernel_launch(void* const* d_in, const int* in_sizes, int n_in,
                              void* d_out, int out_size, void* d_ws, size_t ws_size,
                              hipStream_t stream) {
    const float* I = (const float*)d_in[0];  // (N, D) fp32
    const float* A = (const float*)d_in[1];  // (C, 8, 4) fp32
    const float* T = (const float*)d_in[2];  // (C*15,) fp32
    const float* L = (const float*)d_in[3];  // (M, C, K) fp32
    // d_in[4] = S, d_in[5] = B: structural constants, hard-coded.

    uint4* Bpk = (uint4*)d_ws;               // 1 MB fp16 LUT in MFMA-B fragment order
    float* out = (float*)d_out;              // (N, M) fp32

    hipLaunchKernelGGL(pack_bfrag, dim3(256), dim3(256), 0, stream, L, Bpk);
    hipLaunchKernelGGL(fused_mfma, dim3(NN / 16 / 4 * 2), dim3(256), 0, stream, I, A, T, Bpk, out);
}